// Round 13
// baseline (588.180 us; speedup 1.0000x reference)
//
#include <hip/hip_runtime.h>
#include <hip/hip_fp16.h>
#include <cstdint>

#define D 128
#define NEG_SLOPE 0.2f
#define LN_EPS 1e-5f
#define SM_EPS 1e-16f

typedef _Float16 f16x8 __attribute__((ext_vector_type(8)));
typedef float f32x4 __attribute__((ext_vector_type(4)));

// ---------------- CSR build (real edges only; self-loops analytic) ----------------

__global__ void hist_dst(const int* __restrict__ dst, int E,
                         int* __restrict__ deg, int* __restrict__ rank) {
    int e = blockIdx.x * blockDim.x + threadIdx.x;
    if (e < E) rank[e] = atomicAdd(&deg[dst[e]], 1);
}

__global__ void scanA(const int* __restrict__ deg, int n,
                      int* __restrict__ excl, int* __restrict__ bsums) {
    __shared__ int s[256];
    int t = threadIdx.x;
    int v = blockIdx.x * 256 + t;
    int d = (v < n) ? deg[v] : 0;
    s[t] = d;
    __syncthreads();
    for (int off = 1; off < 256; off <<= 1) {
        int tv = (t >= off) ? s[t - off] : 0;
        __syncthreads();
        s[t] += tv;
        __syncthreads();
    }
    if (v < n) excl[v] = s[t] - d;
    if (t == 255) bsums[blockIdx.x] = s[255];
}

__global__ void scanB(int* __restrict__ bsums, int nb) {
    __shared__ int s[512];
    int t = threadIdx.x;
    int v = (t < nb) ? bsums[t] : 0;
    s[t] = v;
    __syncthreads();
    for (int off = 1; off < 512; off <<= 1) {
        int tv = (t >= off) ? s[t - off] : 0;
        __syncthreads();
        s[t] += tv;
        __syncthreads();
    }
    if (t < nb) bsums[t] = s[t] - v;   // exclusive
}

__global__ void scanC(int* __restrict__ rowptr, const int* __restrict__ bsums,
                      int n, int total) {
    int v = blockIdx.x * blockDim.x + threadIdx.x;
    if (v < n) rowptr[v] += bsums[v >> 8];
    if (v == 0) rowptr[n] = total;
}

__global__ void fill_csr(const int* __restrict__ src, const int* __restrict__ dst,
                         const int* __restrict__ rank, int E,
                         const int* __restrict__ rowptr, int* __restrict__ col) {
    int e = blockIdx.x * blockDim.x + threadIdx.x;
    if (e >= E) return;
    int d = dst[e];
    int p = rowptr[d] + rank[e];
    atomicExch(&col[p], src[e]);   // fire-and-forget scattered store
}

// ---------------- prep_w: Wt = W^T (fp16) + w_s = W@a_src, w_d = W@a_dst ----------

__global__ void prep_w(const float* __restrict__ W, const float* __restrict__ a_src,
                       const float* __restrict__ a_dst, __half* __restrict__ Wt,
                       float* __restrict__ wsv, float* __restrict__ wdv) {
    int l = blockIdx.x >> 3;
    int part = blockIdx.x & 7;
    const float* Wl = W + (size_t)l * D * D;
    __half* Wtl = Wt + (size_t)l * D * D;
    int t = threadIdx.x;
    int c0 = part * 16;

    __shared__ float sT[128][17];
    #pragma unroll
    for (int i = 0; i < 8; ++i) {
        int id = i * 256 + t;          // 0..2047
        int k = id >> 4, c = id & 15;
        sT[k][c] = Wl[(size_t)k * D + c0 + c];
    }
    __syncthreads();
    {
        int c = t >> 4, kg = t & 15;
        union { __half hv[8]; float4 f4; } u;
        #pragma unroll
        for (int j = 0; j < 8; ++j) u.hv[j] = __float2half(sT[kg * 8 + j][c]);
        *(float4*)(Wtl + (size_t)(c0 + c) * D + kg * 8) = u.f4;
    }

    if (part == 0) {
        __shared__ float sA[D], sD[D];
        if (t < D) { sA[t] = a_src[l * D + t]; sD[t] = a_dst[l * D + t]; }
        __syncthreads();
        if (t < D) {
            float ps = 0.f, pd = 0.f;
            for (int c = 0; c < D; ++c) {
                float wv = Wl[(size_t)t * D + c];
                ps += wv * sA[c];
                pd += wv * sD[c];
            }
            wsv[l * D + t] = ps;
            wdv[l * D + t] = pd;
        }
    }
}

// ---------------- MFMA GEMM: h = x@W + alpha dots; C staged via LDS ----------------
// r12 profile insight: direct h-store was 64x 2B scattered stores per thread.
// Now: MFMA C -> sWb as 2B LDS writes (2-way bank alias = free), barrier,
// read back float4, 8x16B coalesced global stores per thread.

__global__ __launch_bounds__(256) void gemm_mfma(
        const float* __restrict__ x, const __half* __restrict__ Wt,
        const float* __restrict__ wsv, const float* __restrict__ wdv,
        __half* __restrict__ h, float* __restrict__ as_, float* __restrict__ ad_, int n) {
    __shared__ char sXa[32768];
    __shared__ char sWb[32768];
    int t = threadIdx.x;
    int row0 = blockIdx.x * 128;
    int lane = t & 63;
    int w = t >> 6;
    int wrow = (w >> 1) * 64;
    int wcol = (w & 1) * 64;

    const float4* xv = (const float4*)x;
    #pragma unroll
    for (int i = 0; i < 16; ++i) {
        int slot = i * 256 + t;
        int r = slot >> 5;
        int c4 = slot & 31;
        int gr = row0 + r;
        float4 v = (gr < n) ? xv[(size_t)gr * 32 + c4] : make_float4(0.f, 0.f, 0.f, 0.f);
        union { __half2 q[2]; float2 f; } u;
        u.q[0] = __floats2half2_rn(v.x, v.y);
        u.q[1] = __floats2half2_rn(v.z, v.w);
        *(float2*)(sXa + r * 256 + ((c4 * 8) ^ ((r & 7) << 4))) = u.f;
    }
    const float4* wv = (const float4*)Wt;
    #pragma unroll
    for (int i = 0; i < 8; ++i) {
        int chunk = i * 256 + t;
        int r = chunk >> 4;
        int c16 = chunk & 15;
        float4 v = wv[chunk];
        *(float4*)(sWb + r * 256 + ((c16 * 16) ^ ((r & 7) << 4))) = v;
    }
    __syncthreads();

    f32x4 acc[4][4];
    #pragma unroll
    for (int a = 0; a < 4; ++a)
        #pragma unroll
        for (int b = 0; b < 4; ++b) acc[a][b] = (f32x4){0.f, 0.f, 0.f, 0.f};

    #pragma unroll
    for (int ks = 0; ks < 4; ++ks) {
        int kbyte = ks * 64 + (lane >> 4) * 16;
        f16x8 aF[4], bF[4];
        #pragma unroll
        for (int tt = 0; tt < 4; ++tt) {
            int ra = wrow + tt * 16 + (lane & 15);
            aF[tt] = *(f16x8*)(sXa + ra * 256 + (kbyte ^ ((ra & 7) << 4)));
            int rb = wcol + tt * 16 + (lane & 15);
            bF[tt] = *(f16x8*)(sWb + rb * 256 + (kbyte ^ ((rb & 7) << 4)));
        }
        #pragma unroll
        for (int tr = 0; tr < 4; ++tr)
            #pragma unroll
            for (int tc = 0; tc < 4; ++tc)
                acc[tr][tc] = __builtin_amdgcn_mfma_f32_16x16x32_f16(aF[tr], bF[tc], acc[tr][tc], 0, 0, 0);
    }

    // alpha dots from LDS x-tile (before sWb is recycled): 2 threads per row
    {
        int r = t >> 1, hh = t & 1;
        float ps = 0.f, pd = 0.f;
        const float4* s4 = (const float4*)wsv + hh * 16;
        const float4* d4 = (const float4*)wdv + hh * 16;
        #pragma unroll
        for (int g = 0; g < 8; ++g) {
            int kbyte = hh * 128 + g * 16;
            f16x8 xa = *(f16x8*)(sXa + r * 256 + (kbyte ^ ((r & 7) << 4)));
            float4 sa = s4[g * 2], sb = s4[g * 2 + 1];
            float4 da = d4[g * 2], db = d4[g * 2 + 1];
            ps += (float)xa[0] * sa.x + (float)xa[1] * sa.y + (float)xa[2] * sa.z + (float)xa[3] * sa.w
                + (float)xa[4] * sb.x + (float)xa[5] * sb.y + (float)xa[6] * sb.z + (float)xa[7] * sb.w;
            pd += (float)xa[0] * da.x + (float)xa[1] * da.y + (float)xa[2] * da.z + (float)xa[3] * da.w
                + (float)xa[4] * db.x + (float)xa[5] * db.y + (float)xa[6] * db.z + (float)xa[7] * db.w;
        }
        ps += __shfl_xor(ps, 1);
        pd += __shfl_xor(pd, 1);
        if (hh == 0 && row0 + r < n) { as_[row0 + r] = ps; ad_[row0 + r] = pd; }
    }

    // stage C tile into sWb (done being read by MFMA), then coalesced store
    __syncthreads();
    #pragma unroll
    for (int tr = 0; tr < 4; ++tr) {
        int rloc = wrow + tr * 16 + (lane >> 4) * 4;
        #pragma unroll
        for (int reg = 0; reg < 4; ++reg) {
            int r = rloc + reg;
            int swz = (r & 7) << 4;
            #pragma unroll
            for (int tc = 0; tc < 4; ++tc) {
                int c = wcol + tc * 16 + (lane & 15);
                *(__half*)(sWb + r * 256 + ((c * 2) ^ swz)) = __float2half(acc[tr][tc][reg]);
            }
        }
    }
    __syncthreads();
    {
        int r = t >> 1;
        int gr = row0 + r;
        if (gr < n) {
            int halfsel = (t & 1) * 128;   // byte offset of this thread's 128B half-row
            int swz = (r & 7) << 4;
            #pragma unroll
            for (int j = 0; j < 8; ++j) {
                float4 v = *(float4*)(sWb + r * 256 + ((halfsel + j * 16) ^ swz));
                *(float4*)(h + (size_t)gr * D + (t & 1) * 64 + j * 8) = v;
            }
        }
    }
}

// ---------------- fused softmax-aggregate + residual + LN + ReLU ----------------
// one wave per dst node; (src, half2 weight) packed in int2 LDS (1x ds_read_b64
// per edge); pass 2 inner loop is a 2-deep software pipeline (h-load for edge
// i+4 issued before edge i's FMAs) -> 2x gather MLP per 16-lane group.

__global__ __launch_bounds__(256) void aggregate(
        const float* __restrict__ xin, const __half* __restrict__ h,
        const float* __restrict__ as_, const float* __restrict__ ad_,
        const int* __restrict__ col, const int* __restrict__ rowptr,
        const float* __restrict__ bias, const float* __restrict__ gamma,
        const float* __restrict__ beta, float* __restrict__ xout, int n) {
    __shared__ int2 sSW[4][64];
    int tid = threadIdx.x;
    int wslot = tid >> 6;
    int lane = tid & 63;
    int wid = (int)((blockIdx.x * blockDim.x + tid) >> 6);
    if (wid >= n) return;
    int v = wid;
    int grp = lane >> 4;
    int gl  = lane & 15;
    int start = rowptr[v], end = rowptr[v + 1];
    float adv = ad_[v];
    float self_a = as_[v] + adv;
    self_a = (self_a > 0.f) ? self_a : NEG_SLOPE * self_a;

    // pass 1: max over edges; keep chunk-0 (src, logit) in regs
    float mval = self_a;
    int   s0r = 0;
    float a0r = -1e30f;
    for (int cb = start; cb < end; cb += 64) {
        int e = cb + lane;
        int   sl = 0;
        float al = -1e30f;
        if (e < end) {
            sl = col[e];
            float aa = as_[sl] + adv;
            al = (aa > 0.f) ? aa : NEG_SLOPE * aa;
        }
        if (cb == start) { s0r = sl; a0r = al; }
        mval = fmaxf(mval, al);
    }
    #pragma unroll
    for (int d = 32; d >= 1; d >>= 1) mval = fmaxf(mval, __shfl_xor(mval, d));

    float wl = __expf(a0r - mval);
    float sacc = wl;
    {
        __half2 wp = __float2half2_rn(wl);
        sSW[wslot][lane] = make_int2(s0r, *(int*)&wp);
    }

    __half2 hacc[4];
    #pragma unroll
    for (int j = 0; j < 4; ++j) hacc[j] = __float2half2_rn(0.f);

    const float4* h4 = (const float4*)h;

    for (int cb = start; cb < end; cb += 64) {
        if (cb != start) {   // deg > 64 only
            int e = cb + lane;
            int   sl = 0;
            float al = -1e30f;
            if (e < end) {
                sl = col[e];
                float aa = as_[sl] + adv;
                al = (aa > 0.f) ? aa : NEG_SLOPE * aa;
            }
            float wl2 = __expf(al - mval);
            sacc += wl2;
            __half2 wp = __float2half2_rn(wl2);
            sSW[wslot][lane] = make_int2(sl, *(int*)&wp);
        }
        int cnt = min(64, end - cb);
        int i = grp;
        if (i < cnt) {
            int2 e0 = sSW[wslot][i];
            float4 u0 = h4[(size_t)e0.x * 16 + gl];
            for (i += 4; i < cnt; i += 4) {
                int2 e1 = sSW[wslot][i];
                float4 u1 = h4[(size_t)e1.x * 16 + gl];   // issue next load early
                __half2 w2 = *(__half2*)&e0.y;
                union { float4 f4; __half2 h2[4]; } u;
                u.f4 = u0;
                #pragma unroll
                for (int j = 0; j < 4; ++j) hacc[j] = __hfma2(u.h2[j], w2, hacc[j]);
                e0 = e1; u0 = u1;
            }
            __half2 w2 = *(__half2*)&e0.y;
            union { float4 f4; __half2 h2[4]; } u;
            u.f4 = u0;
            #pragma unroll
            for (int j = 0; j < 4; ++j) hacc[j] = __hfma2(u.h2[j], w2, hacc[j]);
        }
    }
    #pragma unroll
    for (int d = 32; d >= 1; d >>= 1) sacc += __shfl_xor(sacc, d);

    float acc[8];
    #pragma unroll
    for (int j = 0; j < 4; ++j) {
        float2 f = __half22float2(hacc[j]);
        acc[2 * j] = f.x;
        acc[2 * j + 1] = f.y;
    }
    #pragma unroll
    for (int j = 0; j < 8; ++j) {
        acc[j] += __shfl_xor(acc[j], 16);
        acc[j] += __shfl_xor(acc[j], 32);
    }

    float w_self = __expf(self_a - mval);
    sacc += w_self;
    {
        union { float4 f4; __half2 h2[4]; } u;
        u.f4 = h4[(size_t)v * 16 + gl];
        #pragma unroll
        for (int j = 0; j < 4; ++j) {
            float2 f = __half22float2(u.h2[j]);
            acc[2 * j]     += w_self * f.x;
            acc[2 * j + 1] += w_self * f.y;
        }
    }
    float inv = 1.f / (sacc + SM_EPS);

    const float4* xr = (const float4*)(xin + (size_t)v * D) + gl * 2;
    float4 xa = xr[0], xb = xr[1];
    const float4* b4 = (const float4*)bias + gl * 2;
    float4 ba = b4[0], bb = b4[1];
    float y[8];
    y[0] = xa.x + acc[0] * inv + ba.x;
    y[1] = xa.y + acc[1] * inv + ba.y;
    y[2] = xa.z + acc[2] * inv + ba.z;
    y[3] = xa.w + acc[3] * inv + ba.w;
    y[4] = xb.x + acc[4] * inv + bb.x;
    y[5] = xb.y + acc[5] * inv + bb.y;
    y[6] = xb.z + acc[6] * inv + bb.z;
    y[7] = xb.w + acc[7] * inv + bb.w;

    float s2 = 0.f;
    #pragma unroll
    for (int j = 0; j < 8; ++j) s2 += y[j];
    #pragma unroll
    for (int d = 8; d >= 1; d >>= 1) s2 += __shfl_xor(s2, d);
    float mu = s2 * (1.f / 128.f);
    float vs = 0.f;
    #pragma unroll
    for (int j = 0; j < 8; ++j) { float dd = y[j] - mu; vs += dd * dd; }
    #pragma unroll
    for (int d = 8; d >= 1; d >>= 1) vs += __shfl_xor(vs, d);
    float rstd = rsqrtf(vs * (1.f / 128.f) + LN_EPS);

    const float4* g4 = (const float4*)gamma + gl * 2;
    const float4* t4 = (const float4*)beta + gl * 2;
    float4 ga = g4[0], gb = g4[1];
    float4 ta = t4[0], tb = t4[1];
    float4 oa, ob;
    oa.x = fmaxf((y[0] - mu) * rstd * ga.x + ta.x, 0.f);
    oa.y = fmaxf((y[1] - mu) * rstd * ga.y + ta.y, 0.f);
    oa.z = fmaxf((y[2] - mu) * rstd * ga.z + ta.z, 0.f);
    oa.w = fmaxf((y[3] - mu) * rstd * ga.w + ta.w, 0.f);
    ob.x = fmaxf((y[4] - mu) * rstd * gb.x + tb.x, 0.f);
    ob.y = fmaxf((y[5] - mu) * rstd * gb.y + tb.y, 0.f);
    ob.z = fmaxf((y[6] - mu) * rstd * gb.z + tb.z, 0.f);
    ob.w = fmaxf((y[7] - mu) * rstd * gb.w + tb.w, 0.f);

    if (lane < 16) {
        float4* o4 = (float4*)(xout + (size_t)v * D) + gl * 2;
        o4[0] = oa;
        o4[1] = ob;
    }
}

// ---------------- launch ----------------

extern "C" void kernel_launch(void* const* d_in, const int* in_sizes, int n_in,
                              void* d_out, int out_size, void* d_ws, size_t ws_size,
                              hipStream_t stream) {
    const float* x       = (const float*)d_in[0];
    const int*   edge    = (const int*)d_in[1];
    const float* W       = (const float*)d_in[2];
    const float* att_src = (const float*)d_in[3];
    const float* att_dst = (const float*)d_in[4];
    const float* bias    = (const float*)d_in[5];
    const float* gamma   = (const float*)d_in[6];
    const float* beta    = (const float*)d_in[7];
    float* out = (float*)d_out;

    const int N = in_sizes[0] / D;       // 100000
    const int E = in_sizes[1] / 2;       // 1600000

    const int* src = edge;
    const int* dst = edge + E;

    // ---- workspace carve ----
    char* ws = (char*)d_ws;
    size_t off = 0;
    auto carve = [&](size_t bytes) -> char* {
        char* p = ws + off;
        off = (off + bytes + 511) & ~(size_t)511;
        return p;
    };
    int*    rowptr = (int*)carve((size_t)(N + 1) * 4);
    int*    deg    = (int*)carve((size_t)N * 4);
    int*    bsums  = (int*)carve(512 * 4);
    int*    col    = (int*)carve((size_t)E * 4);
    int*    rank   = (int*)carve((size_t)E * 4);
    __half* h      = (__half*)carve((size_t)N * D * 2);
    float*  as_    = (float*)carve((size_t)N * 4);
    float*  ad_    = (float*)carve((size_t)N * 4);
    float*  x1     = (float*)carve((size_t)N * D * 4);
    __half* Wt     = (__half*)carve((size_t)3 * D * D * 2);
    float*  wsv    = (float*)carve((size_t)3 * D * 4);
    float*  wdv    = (float*)carve((size_t)3 * D * 4);
    (void)ws_size;

    const int TPB = 256;
    int nbN = (N + TPB - 1) / TPB;       // 391 (<=512 for scanB)
    int nbE = (E + TPB - 1) / TPB;

    // ---- W prep (independent of CSR) ----
    prep_w<<<24, TPB, 0, stream>>>(W, att_src, att_dst, Wt, wsv, wdv);

    // ---- CSR build ----
    hipMemsetAsync(deg, 0, (size_t)N * 4, stream);
    hist_dst<<<nbE, TPB, 0, stream>>>(dst, E, deg, rank);
    scanA<<<nbN, TPB, 0, stream>>>(deg, N, rowptr, bsums);
    scanB<<<1, 512, 0, stream>>>(bsums, nbN);
    scanC<<<nbN, TPB, 0, stream>>>(rowptr, bsums, N, E);
    fill_csr<<<nbE, TPB, 0, stream>>>(src, dst, rank, E, rowptr, col);

    // ---- 3 levels (x -> x1 -> x1 -> out) ----
    int gemmGrid = (N + 127) / 128;           // 782
    int aggGrid  = (N * 64 + TPB - 1) / TPB;  // wave-per-node

    const float* xin = x;
    float* bufs[3] = { x1, x1, out };
    for (int l = 0; l < 3; ++l) {
        const __half* Wtl = Wt + (size_t)l * D * D;
        const float*  wsl = wsv + (size_t)l * D;
        const float*  wdl = wdv + (size_t)l * D;
        const float*  bl  = bias + (size_t)l * D;
        const float*  gl  = gamma + (size_t)l * D;
        const float*  btl = beta + (size_t)l * D;
        float* xout = bufs[l];

        gemm_mfma<<<gemmGrid, TPB, 0, stream>>>(xin, Wtl, wsl, wdl, h, as_, ad_, N);
        aggregate<<<aggGrid, TPB, 0, stream>>>(xin, h, as_, ad_, col, rowptr,
                                               bl, gl, btl, xout, N);
        xin = xout;
    }
}

// Round 14
// 580.605 us; speedup vs baseline: 1.0130x; 1.0130x over previous
//
#include <hip/hip_runtime.h>
#include <hip/hip_fp16.h>
#include <cstdint>

#define D 128
#define NEG_SLOPE 0.2f
#define LN_EPS 1e-5f
#define SM_EPS 1e-16f

typedef _Float16 f16x8 __attribute__((ext_vector_type(8)));
typedef float f32x4 __attribute__((ext_vector_type(4)));

// ---------------- CSR build (real edges only; self-loops analytic) ----------------

__global__ void hist_dst(const int* __restrict__ dst, int E,
                         int* __restrict__ deg, int* __restrict__ rank) {
    int e = blockIdx.x * blockDim.x + threadIdx.x;
    if (e < E) rank[e] = atomicAdd(&deg[dst[e]], 1);
}

__global__ void scanA(const int* __restrict__ deg, int n,
                      int* __restrict__ excl, int* __restrict__ bsums) {
    __shared__ int s[256];
    int t = threadIdx.x;
    int v = blockIdx.x * 256 + t;
    int d = (v < n) ? deg[v] : 0;
    s[t] = d;
    __syncthreads();
    for (int off = 1; off < 256; off <<= 1) {
        int tv = (t >= off) ? s[t - off] : 0;
        __syncthreads();
        s[t] += tv;
        __syncthreads();
    }
    if (v < n) excl[v] = s[t] - d;
    if (t == 255) bsums[blockIdx.x] = s[255];
}

__global__ void scanB(int* __restrict__ bsums, int nb) {
    __shared__ int s[512];
    int t = threadIdx.x;
    int v = (t < nb) ? bsums[t] : 0;
    s[t] = v;
    __syncthreads();
    for (int off = 1; off < 512; off <<= 1) {
        int tv = (t >= off) ? s[t - off] : 0;
        __syncthreads();
        s[t] += tv;
        __syncthreads();
    }
    if (t < nb) bsums[t] = s[t] - v;   // exclusive
}

__global__ void scanC(int* __restrict__ rowptr, const int* __restrict__ bsums,
                      int n, int total) {
    int v = blockIdx.x * blockDim.x + threadIdx.x;
    if (v < n) rowptr[v] += bsums[v >> 8];
    if (v == 0) rowptr[n] = total;
}

__global__ void fill_csr(const int* __restrict__ src, const int* __restrict__ dst,
                         const int* __restrict__ rank, int E,
                         const int* __restrict__ rowptr, int* __restrict__ col) {
    int e = blockIdx.x * blockDim.x + threadIdx.x;
    if (e >= E) return;
    int d = dst[e];
    int p = rowptr[d] + rank[e];
    atomicExch(&col[p], src[e]);   // fire-and-forget scattered store
}

// ---------------- prep_w: Wt = W^T (fp16) + w_s = W@a_src, w_d = W@a_dst ----------

__global__ void prep_w(const float* __restrict__ W, const float* __restrict__ a_src,
                       const float* __restrict__ a_dst, __half* __restrict__ Wt,
                       float* __restrict__ wsv, float* __restrict__ wdv) {
    int l = blockIdx.x >> 3;
    int part = blockIdx.x & 7;
    const float* Wl = W + (size_t)l * D * D;
    __half* Wtl = Wt + (size_t)l * D * D;
    int t = threadIdx.x;
    int c0 = part * 16;

    __shared__ float sT[128][17];
    #pragma unroll
    for (int i = 0; i < 8; ++i) {
        int id = i * 256 + t;          // 0..2047
        int k = id >> 4, c = id & 15;
        sT[k][c] = Wl[(size_t)k * D + c0 + c];
    }
    __syncthreads();
    {
        int c = t >> 4, kg = t & 15;
        union { __half hv[8]; float4 f4; } u;
        #pragma unroll
        for (int j = 0; j < 8; ++j) u.hv[j] = __float2half(sT[kg * 8 + j][c]);
        *(float4*)(Wtl + (size_t)(c0 + c) * D + kg * 8) = u.f4;
    }

    if (part == 0) {
        __shared__ float sA[D], sD[D];
        if (t < D) { sA[t] = a_src[l * D + t]; sD[t] = a_dst[l * D + t]; }
        __syncthreads();
        if (t < D) {
            float ps = 0.f, pd = 0.f;
            for (int c = 0; c < D; ++c) {
                float wv = Wl[(size_t)t * D + c];
                ps += wv * sA[c];
                pd += wv * sD[c];
            }
            wsv[l * D + t] = ps;
            wdv[l * D + t] = pd;
        }
    }
}

// ---------------- MFMA GEMM v2: no x-staging, 32KB LDS, fused fp32 alpha dots ----
// Block 256 = 4 waves; each wave owns 32 rows x 128 cols. A-frags load direct
// from global x (fp32 -> fp16 in reg); Wt staged once in 32KB swizzled LDS
// (3-4 blocks/CU -> block-level overlap of load/compute/store phases).
// After MFMA the Wt buffer is recycled to stage C for coalesced 16B h-stores.

__global__ __launch_bounds__(256) void gemm_mfma(
        const float* __restrict__ x, const __half* __restrict__ Wt,
        const float* __restrict__ wsv, const float* __restrict__ wdv,
        __half* __restrict__ h, float* __restrict__ as_, float* __restrict__ ad_, int n) {
    __shared__ char sWb[32768];
    int t = threadIdx.x;
    int lane = t & 63;
    int w = t >> 6;
    int rowB = blockIdx.x * 128;      // block row base
    int row0 = rowB + w * 32;         // wave row base
    int rl = lane & 15;               // row-in-16 / C col
    int kg = lane >> 4;               // k-subgroup 0..3

    // stage Wt swizzled (8 x 16B per thread)
    const float4* wv = (const float4*)Wt;
    #pragma unroll
    for (int i = 0; i < 8; ++i) {
        int chunk = i * 256 + t;      // 2048 chunks of 16B
        int r = chunk >> 4;
        int c16 = chunk & 15;
        float4 v = wv[chunk];
        *(float4*)(sWb + r * 256 + ((c16 * 16) ^ ((r & 7) << 4))) = v;
    }
    __syncthreads();

    f32x4 acc[2][8];
    #pragma unroll
    for (int a = 0; a < 2; ++a)
        #pragma unroll
        for (int b = 0; b < 8; ++b) acc[a][b] = (f32x4){0.f, 0.f, 0.f, 0.f};
    float dsv[2] = {0.f, 0.f}, ddv[2] = {0.f, 0.f};

    #pragma unroll
    for (int ks = 0; ks < 4; ++ks) {
        int kf = ks * 32 + kg * 8;            // fp32 element offset
        int kbyte = ks * 64 + kg * 16;        // fp16 byte offset

        f16x8 bF[8];
        #pragma unroll
        for (int tc = 0; tc < 8; ++tc) {
            int rb = tc * 16 + rl;
            bF[tc] = *(f16x8*)(sWb + rb * 256 + (kbyte ^ ((rb & 7) << 4)));
        }

        float4 wsa = *(const float4*)(wsv + kf);
        float4 wsb = *(const float4*)(wsv + kf + 4);
        float4 wda = *(const float4*)(wdv + kf);
        float4 wdb = *(const float4*)(wdv + kf + 4);

        f16x8 aF[2];
        #pragma unroll
        for (int tt = 0; tt < 2; ++tt) {
            int gr = row0 + tt * 16 + rl;
            float4 va = make_float4(0.f, 0.f, 0.f, 0.f);
            float4 vb = va;
            if (gr < n) {
                const float* xr = x + (size_t)gr * D + kf;
                va = *(const float4*)xr;
                vb = *(const float4*)(xr + 4);
            }
            union { __half2 q[4]; f16x8 f; } u;
            u.q[0] = __floats2half2_rn(va.x, va.y);
            u.q[1] = __floats2half2_rn(va.z, va.w);
            u.q[2] = __floats2half2_rn(vb.x, vb.y);
            u.q[3] = __floats2half2_rn(vb.z, vb.w);
            aF[tt] = u.f;
            dsv[tt] += va.x * wsa.x + va.y * wsa.y + va.z * wsa.z + va.w * wsa.w
                     + vb.x * wsb.x + vb.y * wsb.y + vb.z * wsb.z + vb.w * wsb.w;
            ddv[tt] += va.x * wda.x + va.y * wda.y + va.z * wda.z + va.w * wda.w
                     + vb.x * wdb.x + vb.y * wdb.y + vb.z * wdb.z + vb.w * wdb.w;
        }

        #pragma unroll
        for (int tt = 0; tt < 2; ++tt)
            #pragma unroll
            for (int tc = 0; tc < 8; ++tc)
                acc[tt][tc] = __builtin_amdgcn_mfma_f32_16x16x32_f16(aF[tt], bF[tc], acc[tt][tc], 0, 0, 0);
    }

    // alpha dots: sum the 4 k-subgroups (lanes l, l^16, l^32, l^48 share a row)
    #pragma unroll
    for (int tt = 0; tt < 2; ++tt) {
        dsv[tt] += __shfl_xor(dsv[tt], 16);
        dsv[tt] += __shfl_xor(dsv[tt], 32);
        ddv[tt] += __shfl_xor(ddv[tt], 16);
        ddv[tt] += __shfl_xor(ddv[tt], 32);
    }
    if (lane < 16) {
        #pragma unroll
        for (int tt = 0; tt < 2; ++tt) {
            int gr = row0 + tt * 16 + lane;
            if (gr < n) { as_[gr] = dsv[tt]; ad_[gr] = ddv[tt]; }
        }
    }

    // recycle sWb: stage C (fp16) then coalesced 16B stores.
    // C-phase swizzle ((r>>2)&3)<<5: the 4 quarter-wave row-groups (stride 4)
    // land in disjoint 32B bank windows -> conflict-free 2B writes.
    __syncthreads();
    #pragma unroll
    for (int tt = 0; tt < 2; ++tt) {
        #pragma unroll
        for (int reg = 0; reg < 4; ++reg) {
            int rloc = w * 32 + tt * 16 + kg * 4 + reg;
            int swz = ((rloc >> 2) & 3) << 5;
            #pragma unroll
            for (int tc = 0; tc < 8; ++tc) {
                int c = tc * 16 + rl;
                *(__half*)(sWb + rloc * 256 + ((c * 2) ^ swz)) = __float2half(acc[tt][tc][reg]);
            }
        }
    }
    __syncthreads();
    {
        int r = t >> 1;
        int gr = rowB + r;
        if (gr < n) {
            int halfs = (t & 1) * 128;
            int swz = ((r >> 2) & 3) << 5;
            #pragma unroll
            for (int j = 0; j < 8; ++j) {
                float4 v = *(float4*)(sWb + r * 256 + ((halfs + j * 16) ^ swz));
                *(float4*)(h + (size_t)gr * D + (t & 1) * 64 + j * 8) = v;
            }
        }
    }
}

// ---------------- fused softmax-aggregate + residual + LN + ReLU ----------------

__global__ __launch_bounds__(256) void aggregate(
        const float* __restrict__ xin, const __half* __restrict__ h,
        const float* __restrict__ as_, const float* __restrict__ ad_,
        const int* __restrict__ col, const int* __restrict__ rowptr,
        const float* __restrict__ bias, const float* __restrict__ gamma,
        const float* __restrict__ beta, float* __restrict__ xout, int n) {
    __shared__ int2 sSW[4][64];
    int tid = threadIdx.x;
    int wslot = tid >> 6;
    int lane = tid & 63;
    int wid = (int)((blockIdx.x * blockDim.x + tid) >> 6);
    if (wid >= n) return;
    int v = wid;
    int grp = lane >> 4;
    int gl  = lane & 15;
    int start = rowptr[v], end = rowptr[v + 1];
    float adv = ad_[v];
    float self_a = as_[v] + adv;
    self_a = (self_a > 0.f) ? self_a : NEG_SLOPE * self_a;

    float mval = self_a;
    int   s0r = 0;
    float a0r = -1e30f;
    for (int cb = start; cb < end; cb += 64) {
        int e = cb + lane;
        int   sl = 0;
        float al = -1e30f;
        if (e < end) {
            sl = col[e];
            float aa = as_[sl] + adv;
            al = (aa > 0.f) ? aa : NEG_SLOPE * aa;
        }
        if (cb == start) { s0r = sl; a0r = al; }
        mval = fmaxf(mval, al);
    }
    #pragma unroll
    for (int d = 32; d >= 1; d >>= 1) mval = fmaxf(mval, __shfl_xor(mval, d));

    float wl = __expf(a0r - mval);
    float sacc = wl;
    {
        __half2 wp = __float2half2_rn(wl);
        sSW[wslot][lane] = make_int2(s0r, *(int*)&wp);
    }

    __half2 hacc[4];
    #pragma unroll
    for (int j = 0; j < 4; ++j) hacc[j] = __float2half2_rn(0.f);

    const float4* h4 = (const float4*)h;

    for (int cb = start; cb < end; cb += 64) {
        if (cb != start) {   // deg > 64 only
            int e = cb + lane;
            int   sl = 0;
            float al = -1e30f;
            if (e < end) {
                sl = col[e];
                float aa = as_[sl] + adv;
                al = (aa > 0.f) ? aa : NEG_SLOPE * aa;
            }
            float wl2 = __expf(al - mval);
            sacc += wl2;
            __half2 wp = __float2half2_rn(wl2);
            sSW[wslot][lane] = make_int2(sl, *(int*)&wp);
        }
        int cnt = min(64, end - cb);
        int i = grp;
        if (i < cnt) {
            int2 e0 = sSW[wslot][i];
            float4 u0 = h4[(size_t)e0.x * 16 + gl];
            for (i += 4; i < cnt; i += 4) {
                int2 e1 = sSW[wslot][i];
                float4 u1 = h4[(size_t)e1.x * 16 + gl];   // issue next load early
                __half2 w2 = *(__half2*)&e0.y;
                union { float4 f4; __half2 h2[4]; } u;
                u.f4 = u0;
                #pragma unroll
                for (int j = 0; j < 4; ++j) hacc[j] = __hfma2(u.h2[j], w2, hacc[j]);
                e0 = e1; u0 = u1;
            }
            __half2 w2 = *(__half2*)&e0.y;
            union { float4 f4; __half2 h2[4]; } u;
            u.f4 = u0;
            #pragma unroll
            for (int j = 0; j < 4; ++j) hacc[j] = __hfma2(u.h2[j], w2, hacc[j]);
        }
    }
    #pragma unroll
    for (int d = 32; d >= 1; d >>= 1) sacc += __shfl_xor(sacc, d);

    float acc[8];
    #pragma unroll
    for (int j = 0; j < 4; ++j) {
        float2 f = __half22float2(hacc[j]);
        acc[2 * j] = f.x;
        acc[2 * j + 1] = f.y;
    }
    #pragma unroll
    for (int j = 0; j < 8; ++j) {
        acc[j] += __shfl_xor(acc[j], 16);
        acc[j] += __shfl_xor(acc[j], 32);
    }

    float w_self = __expf(self_a - mval);
    sacc += w_self;
    {
        union { float4 f4; __half2 h2[4]; } u;
        u.f4 = h4[(size_t)v * 16 + gl];
        #pragma unroll
        for (int j = 0; j < 4; ++j) {
            float2 f = __half22float2(u.h2[j]);
            acc[2 * j]     += w_self * f.x;
            acc[2 * j + 1] += w_self * f.y;
        }
    }
    float inv = 1.f / (sacc + SM_EPS);

    const float4* xr = (const float4*)(xin + (size_t)v * D) + gl * 2;
    float4 xa = xr[0], xb = xr[1];
    const float4* b4 = (const float4*)bias + gl * 2;
    float4 ba = b4[0], bb = b4[1];
    float y[8];
    y[0] = xa.x + acc[0] * inv + ba.x;
    y[1] = xa.y + acc[1] * inv + ba.y;
    y[2] = xa.z + acc[2] * inv + ba.z;
    y[3] = xa.w + acc[3] * inv + ba.w;
    y[4] = xb.x + acc[4] * inv + bb.x;
    y[5] = xb.y + acc[5] * inv + bb.y;
    y[6] = xb.z + acc[6] * inv + bb.z;
    y[7] = xb.w + acc[7] * inv + bb.w;

    float s2 = 0.f;
    #pragma unroll
    for (int j = 0; j < 8; ++j) s2 += y[j];
    #pragma unroll
    for (int d = 8; d >= 1; d >>= 1) s2 += __shfl_xor(s2, d);
    float mu = s2 * (1.f / 128.f);
    float vs = 0.f;
    #pragma unroll
    for (int j = 0; j < 8; ++j) { float dd = y[j] - mu; vs += dd * dd; }
    #pragma unroll
    for (int d = 8; d >= 1; d >>= 1) vs += __shfl_xor(vs, d);
    float rstd = rsqrtf(vs * (1.f / 128.f) + LN_EPS);

    const float4* g4 = (const float4*)gamma + gl * 2;
    const float4* t4 = (const float4*)beta + gl * 2;
    float4 ga = g4[0], gb = g4[1];
    float4 ta = t4[0], tb = t4[1];
    float4 oa, ob;
    oa.x = fmaxf((y[0] - mu) * rstd * ga.x + ta.x, 0.f);
    oa.y = fmaxf((y[1] - mu) * rstd * ga.y + ta.y, 0.f);
    oa.z = fmaxf((y[2] - mu) * rstd * ga.z + ta.z, 0.f);
    oa.w = fmaxf((y[3] - mu) * rstd * ga.w + ta.w, 0.f);
    ob.x = fmaxf((y[4] - mu) * rstd * gb.x + tb.x, 0.f);
    ob.y = fmaxf((y[5] - mu) * rstd * gb.y + tb.y, 0.f);
    ob.z = fmaxf((y[6] - mu) * rstd * gb.z + tb.z, 0.f);
    ob.w = fmaxf((y[7] - mu) * rstd * gb.w + tb.w, 0.f);

    if (lane < 16) {
        float4* o4 = (float4*)(xout + (size_t)v * D) + gl * 2;
        o4[0] = oa;
        o4[1] = ob;
    }
}

// ---------------- launch ----------------

extern "C" void kernel_launch(void* const* d_in, const int* in_sizes, int n_in,
                              void* d_out, int out_size, void* d_ws, size_t ws_size,
                              hipStream_t stream) {
    const float* x       = (const float*)d_in[0];
    const int*   edge    = (const int*)d_in[1];
    const float* W       = (const float*)d_in[2];
    const float* att_src = (const float*)d_in[3];
    const float* att_dst = (const float*)d_in[4];
    const float* bias    = (const float*)d_in[5];
    const float* gamma   = (const float*)d_in[6];
    const float* beta    = (const float*)d_in[7];
    float* out = (float*)d_out;

    const int N = in_sizes[0] / D;       // 100000
    const int E = in_sizes[1] / 2;       // 1600000

    const int* src = edge;
    const int* dst = edge + E;

    // ---- workspace carve ----
    char* ws = (char*)d_ws;
    size_t off = 0;
    auto carve = [&](size_t bytes) -> char* {
        char* p = ws + off;
        off = (off + bytes + 511) & ~(size_t)511;
        return p;
    };
    int*    rowptr = (int*)carve((size_t)(N + 1) * 4);
    int*    deg    = (int*)carve((size_t)N * 4);
    int*    bsums  = (int*)carve(512 * 4);
    int*    col    = (int*)carve((size_t)E * 4);
    int*    rank   = (int*)carve((size_t)E * 4);
    __half* h      = (__half*)carve((size_t)N * D * 2);
    float*  as_    = (float*)carve((size_t)N * 4);
    float*  ad_    = (float*)carve((size_t)N * 4);
    float*  x1     = (float*)carve((size_t)N * D * 4);
    __half* Wt     = (__half*)carve((size_t)3 * D * D * 2);
    float*  wsv    = (float*)carve((size_t)3 * D * 4);
    float*  wdv    = (float*)carve((size_t)3 * D * 4);
    (void)ws_size;

    const int TPB = 256;
    int nbN = (N + TPB - 1) / TPB;       // 391 (<=512 for scanB)
    int nbE = (E + TPB - 1) / TPB;

    // ---- W prep (independent of CSR) ----
    prep_w<<<24, TPB, 0, stream>>>(W, att_src, att_dst, Wt, wsv, wdv);

    // ---- CSR build ----
    hipMemsetAsync(deg, 0, (size_t)N * 4, stream);
    hist_dst<<<nbE, TPB, 0, stream>>>(dst, E, deg, rank);
    scanA<<<nbN, TPB, 0, stream>>>(deg, N, rowptr, bsums);
    scanB<<<1, 512, 0, stream>>>(bsums, nbN);
    scanC<<<nbN, TPB, 0, stream>>>(rowptr, bsums, N, E);
    fill_csr<<<nbE, TPB, 0, stream>>>(src, dst, rank, E, rowptr, col);

    // ---- 3 levels (x -> x1 -> x1 -> out) ----
    int gemmGrid = (N + 127) / 128;           // 782
    int aggGrid  = (N * 64 + TPB - 1) / TPB;  // wave-per-node

    const float* xin = x;
    float* bufs[3] = { x1, x1, out };
    for (int l = 0; l < 3; ++l) {
        const __half* Wtl = Wt + (size_t)l * D * D;
        const float*  wsl = wsv + (size_t)l * D;
        const float*  wdl = wdv + (size_t)l * D;
        const float*  bl  = bias + (size_t)l * D;
        const float*  gl  = gamma + (size_t)l * D;
        const float*  btl = beta + (size_t)l * D;
        float* xout = bufs[l];

        gemm_mfma<<<gemmGrid, TPB, 0, stream>>>(xin, Wtl, wsl, wdl, h, as_, ad_, N);
        aggregate<<<aggGrid, TPB, 0, stream>>>(xin, h, as_, ad_, col, rowptr,
                                               bl, gl, btl, xout, N);
        xin = xout;
    }
}